// Round 7
// baseline (1462.587 us; speedup 1.0000x reference)
//
#include <hip/hip_runtime.h>

// RNN scan: h <- tanh(x_t @ W_ih^T + h @ W_hh^T + b), 2048 steps.
// v7: TWO batches per block (128 blocks). v5 proved the step wall is a fixed
// serial-chain floor (issue -28% -> wall 0%): barrier + LDS burst latency +
// DPP/tanh chains. Two independent recurrences share ONE barrier interval and
// the SAME W registers (Whh tile + Wih MFMA frags); their chains interleave
// within each wave, halving the per-batch fixed cost. Body is byte-equivalent
// v5 math duplicated A/B; compute_xw at s==0(A)/s==1(B), staging s==14/15.

#define BATCH 256
#define SEQ   2048
#define HID   128
#define CH    16
#define NCHUNK (SEQ / CH)

typedef __attribute__((ext_vector_type(8))) short bf16x8;
typedef __attribute__((ext_vector_type(4))) float f32x4;
typedef __attribute__((ext_vector_type(2))) float f32x2;

// DPP ctrl: quad_perm[1,0,3,2]=0xB1 (xor1), quad_perm[2,3,0,1]=0x4E (xor2),
// row_ror:4=0x124, row_ror:8=0x128 (rows of 16 lanes on gfx9+)
template <int CTRL>
__device__ __forceinline__ float dpp_movf(float x) {
    return __int_as_float(__builtin_amdgcn_mov_dpp(__float_as_int(x), CTRL, 0xF, 0xF, true));
}

__device__ __forceinline__ float tanh_fast(float x) {
    x = fminf(fmaxf(x, -12.0f), 12.0f);
    float e = __expf(2.0f * x);
    return 1.0f - __fdividef(2.0f, e + 1.0f);
}

// split float -> (hi, lo) bf16 pair capturing ~16 mantissa bits
__device__ __forceinline__ void bf16_split(float v, short& hi, short& lo) {
    unsigned u = __float_as_uint(v);
    unsigned hb = (u + 0x8000u) & 0xFFFF0000u;
    float hf = __uint_as_float(hb);
    float r = v - hf;
    unsigned ru = __float_as_uint(r);
    hi = (short)(hb >> 16);
    lo = (short)((ru + 0x8000u) >> 16);
}

__global__ __launch_bounds__(512, 1) void rnn_scan_kernel(
    const float* __restrict__ x,    // [B, S, 128]
    const float* __restrict__ Wih,  // [128, 128]
    const float* __restrict__ bih,  // [128]
    const float* __restrict__ Whh,  // [128, 128]
    const float* __restrict__ bhh,  // [128]
    float* __restrict__ out)        // [B, 128]
{
    const int b0 = blockIdx.x << 1;    // batches b0, b0+1
    const int t = threadIdx.x;
    const int g = t >> 4;          // row group: rows 4g..4g+3
    const int c = t & 15;          // col group: cols 8c..8c+7 (of h)
    const int colbase = c << 3;
    const int rowbase = g << 2;
    const int lane = t & 63;
    const int w = t >> 6;          // wave 0..7

    __shared__ __align__(16) ushort xbf[2][2][2][CH * HID];  // [batch][buf][hi/lo] (32 KB)
    __shared__ __align__(16) float  xwbuf[2][2][CH * HID];   // [batch][buf] xw+bias (32 KB)
    __shared__ __align__(16) float  hbuf[2][2][192];         // [batch][cur], p(r)=r+4*(r>>3)

    // --- Whh tile (SHARED by both batches): 4 rows x 4 col-pairs = 32 VGPRs ---
    f32x2 wh[4][4];
#pragma unroll
    for (int r = 0; r < 4; ++r) {
        const float* ph = Whh + (rowbase + r) * HID + colbase;
        float4 u0 = *(const float4*)(ph);
        float4 u1 = *(const float4*)(ph + 4);
        wh[r][0] = f32x2{u0.x, u0.y};
        wh[r][1] = f32x2{u0.z, u0.w};
        wh[r][2] = f32x2{u1.x, u1.y};
        wh[r][3] = f32x2{u1.z, u1.w};
    }

    // --- Wih B-fragments (bf16 hi/lo), SHARED. canonical 16x16x32 B layout ---
    const int bcol = (w << 4) + (lane & 15);   // global output col (h row)
    const float biasv = bih[bcol] + bhh[bcol];
    bf16x8 bhi[4], blo[4];
#pragma unroll
    for (int kk = 0; kk < 4; ++kk) {
        const float* src = Wih + bcol * HID + kk * 32 + ((lane >> 4) << 3);
        float4 u0 = *(const float4*)(src);
        float4 u1 = *(const float4*)(src + 4);
        short hh, ll;
        bf16_split(u0.x, hh, ll); bhi[kk][0] = hh; blo[kk][0] = ll;
        bf16_split(u0.y, hh, ll); bhi[kk][1] = hh; blo[kk][1] = ll;
        bf16_split(u0.z, hh, ll); bhi[kk][2] = hh; blo[kk][2] = ll;
        bf16_split(u0.w, hh, ll); bhi[kk][3] = hh; blo[kk][3] = ll;
        bf16_split(u1.x, hh, ll); bhi[kk][4] = hh; blo[kk][4] = ll;
        bf16_split(u1.y, hh, ll); bhi[kk][5] = hh; blo[kk][5] = ll;
        bf16_split(u1.z, hh, ll); bhi[kk][6] = hh; blo[kk][6] = ll;
        bf16_split(u1.w, hh, ll); bhi[kk][7] = hh; blo[kk][7] = ll;
    }

    // reduce-scatter row assignment (as v5)
    const int m = c & 3;
    const int o = ((m & 1) << 1) | ((m >> 1) & 1);   // 0,2,1,3
    const int row0 = rowbase + o;
    const int hw = row0 + ((row0 >> 3) << 2);        // padded index of row0

    const float* xsA = x + (size_t)b0 * (SEQ * HID);
    const float* xsB = xsA + (size_t)(SEQ * HID);

    auto stage_bf16 = [&](float4 q, int bi, int buf) {
        const int srow = t >> 5;
        const int sw = ((srow << 8) + ((t & 31) << 3)) ^ ((srow & 7) << 4);
        short h0, l0, h1, l1, h2, l2, h3, l3;
        bf16_split(q.x, h0, l0); bf16_split(q.y, h1, l1);
        bf16_split(q.z, h2, l2); bf16_split(q.w, h3, l3);
        uint2 ph, pl;
        ph.x = (unsigned)(ushort)h0 | ((unsigned)(ushort)h1 << 16);
        ph.y = (unsigned)(ushort)h2 | ((unsigned)(ushort)h3 << 16);
        pl.x = (unsigned)(ushort)l0 | ((unsigned)(ushort)l1 << 16);
        pl.y = (unsigned)(ushort)l2 | ((unsigned)(ushort)l3 << 16);
        *(uint2*)((char*)&xbf[bi][buf][0][0] + sw) = ph;
        *(uint2*)((char*)&xbf[bi][buf][1][0] + sw) = pl;
    };

    auto compute_xw = [&](int bi, int mm) {
        const int buf = mm & 1;
        const int arow = lane & 15;
        const int rowb = (arow << 8) + ((lane >> 4) << 4);
        const int swz = (arow & 7) << 4;
        const char* hp = (const char*)&xbf[bi][buf][0][0];
        const char* lp = (const char*)&xbf[bi][buf][1][0];
        f32x4 acc0 = {0.0f, 0.0f, 0.0f, 0.0f};
        f32x4 acc1 = {0.0f, 0.0f, 0.0f, 0.0f};
#pragma unroll
        for (int kk = 0; kk < 4; ++kk) {
            const int off = (rowb + kk * 64) ^ swz;
            bf16x8 ah = *(const bf16x8*)(hp + off);
            bf16x8 al = *(const bf16x8*)(lp + off);
            f32x4& acc = (kk & 1) ? acc1 : acc0;
            acc = __builtin_amdgcn_mfma_f32_16x16x32_bf16(ah, bhi[kk], acc, 0, 0, 0);
            acc = __builtin_amdgcn_mfma_f32_16x16x32_bf16(ah, blo[kk], acc, 0, 0, 0);
            acc = __builtin_amdgcn_mfma_f32_16x16x32_bf16(al, bhi[kk], acc, 0, 0, 0);
        }
        float* xw = &xwbuf[bi][buf][0];
        const int crow = (lane >> 4) << 2;
#pragma unroll
        for (int r = 0; r < 4; ++r)
            xw[(crow + r) * HID + bcol] = acc0[r] + acc1[r] + biasv;
    };

    // --- prologue: stage chunks 0,1 for both batches, zero h, xw(0) both ---
    {
        const float4* gpA = (const float4*)xsA;
        const float4* gpB = (const float4*)xsB;
        float4 a0 = gpA[t], a1 = gpA[512 + t];
        float4 c0 = gpB[t], c1 = gpB[512 + t];
        stage_bf16(a0, 0, 0); stage_bf16(a1, 0, 1);
        stage_bf16(c0, 1, 0); stage_bf16(c1, 1, 1);
    }
    if (t < 192) { hbuf[0][0][t] = 0.0f; hbuf[1][0][t] = 0.0f; }
    __syncthreads();
    compute_xw(0, 0);
    compute_xw(1, 0);
    __syncthreads();

    for (int n = 0; n < NCHUNK; ++n) {
        float4 qA, qB;
        const bool pf = (n + 2 < NCHUNK);
        if (pf) {
            const size_t off = (size_t)(n + 2) * (CH * HID);
            qA = ((const float4*)(xsA + off))[t];
            qB = ((const float4*)(xsB + off))[t];
        }
        const float* xwcA = &xwbuf[0][n & 1][0] + row0;
        const float* xwcB = &xwbuf[1][n & 1][0] + row0;
        const float* hA0 = &hbuf[0][0][12 * c];
        const float* hA1 = &hbuf[0][1][12 * c];
        const float* hB0 = &hbuf[1][0][12 * c];
        const float* hB1 = &hbuf[1][1][12 * c];
#pragma unroll
        for (int s = 0; s < CH; ++s) {
            // h reads FIRST (critical path; LDS returns in order), then xw
            const float* hrA = (s & 1) ? hA1 : hA0;
            const float* hrB = (s & 1) ? hB1 : hB0;
            float4 hvA0 = *(const float4*)(hrA);
            float4 hvA1 = *(const float4*)(hrA + 4);
            float4 hvB0 = *(const float4*)(hrB);
            float4 hvB1 = *(const float4*)(hrB + 4);
            float xwvA = xwcA[s * HID];
            float xwvB = xwcB[s * HID];

            f32x2 pA0 = {hvA0.x, hvA0.y}, pA1 = {hvA0.z, hvA0.w};
            f32x2 pA2 = {hvA1.x, hvA1.y}, pA3 = {hvA1.z, hvA1.w};
            f32x2 pB0 = {hvB0.x, hvB0.y}, pB1 = {hvB0.z, hvB0.w};
            f32x2 pB2 = {hvB1.x, hvB1.y}, pB3 = {hvB1.z, hvB1.w};

            float aA[4], aB[4];
#pragma unroll
            for (int r = 0; r < 4; ++r) {
                f32x2 acc = wh[r][0] * pA0;
                acc = __builtin_elementwise_fma(wh[r][1], pA1, acc);
                acc = __builtin_elementwise_fma(wh[r][2], pA2, acc);
                acc = __builtin_elementwise_fma(wh[r][3], pA3, acc);
                aA[r] = acc.x + acc.y;
                f32x2 bcc = wh[r][0] * pB0;
                bcc = __builtin_elementwise_fma(wh[r][1], pB1, bcc);
                bcc = __builtin_elementwise_fma(wh[r][2], pB2, bcc);
                bcc = __builtin_elementwise_fma(wh[r][3], pB3, bcc);
                aB[r] = bcc.x + bcc.y;
            }

            // --- DPP reduce-scatter, both batches interleaved ---
            const bool q0 = (c & 1) != 0;
            const bool q1 = (c & 2) != 0;
            float kA0 = q0 ? aA[2] : aA[0], sA0 = q0 ? aA[0] : aA[2];
            float kA1 = q0 ? aA[3] : aA[1], sA1 = q0 ? aA[1] : aA[3];
            float kB0 = q0 ? aB[2] : aB[0], sB0 = q0 ? aB[0] : aB[2];
            float kB1 = q0 ? aB[3] : aB[1], sB1 = q0 ? aB[1] : aB[3];
            float tA0 = kA0 + dpp_movf<0xB1>(sA0);
            float tA1 = kA1 + dpp_movf<0xB1>(sA1);
            float tB0 = kB0 + dpp_movf<0xB1>(sB0);
            float tB1 = kB1 + dpp_movf<0xB1>(sB1);
            float kA2 = q1 ? tA1 : tA0, sA2 = q1 ? tA0 : tA1;
            float kB2 = q1 ? tB1 : tB0, sB2 = q1 ? tB0 : tB1;
            float uA = kA2 + dpp_movf<0x4E>(sA2);
            float uB = kB2 + dpp_movf<0x4E>(sB2);
            uA += dpp_movf<0x124>(uA);
            uB += dpp_movf<0x124>(uB);
            uA += dpp_movf<0x128>(uA);
            uB += dpp_movf<0x128>(uB);

            float hA = tanh_fast(uA + xwvA);
            float hB = tanh_fast(uB + xwvB);
            if (c < 4) {
                hbuf[0][(s & 1) ^ 1][hw] = hA;
                hbuf[1][(s & 1) ^ 1][hw] = hB;
            }

            // amortized work, spread across different steps:
            if (s == 0 && n + 1 < NCHUNK) compute_xw(0, n + 1);
            if (s == 1 && n + 1 < NCHUNK) compute_xw(1, n + 1);
            if (s == 14 && pf) stage_bf16(qA, 0, n & 1);
            if (s == 15 && pf) stage_bf16(qB, 1, n & 1);

            __syncthreads();
        }
    }
    // after even # of toggles, hbuf[·][0] holds h_final (padded layout)
    if (t < HID) {
        const int pi = t + ((t >> 3) << 2);
        out[(size_t)b0 * HID + t] = hbuf[0][0][pi];
        out[(size_t)(b0 + 1) * HID + t] = hbuf[1][0][pi];
    }
}

extern "C" void kernel_launch(void* const* d_in, const int* in_sizes, int n_in,
                              void* d_out, int out_size, void* d_ws, size_t ws_size,
                              hipStream_t stream) {
    const float* x   = (const float*)d_in[0];
    const float* Wih = (const float*)d_in[1];
    const float* bih = (const float*)d_in[2];
    const float* Whh = (const float*)d_in[3];
    const float* bhh = (const float*)d_in[4];
    float* out = (float*)d_out;

    rnn_scan_kernel<<<BATCH / 2, 512, 0, stream>>>(x, Wih, bih, Whh, bhh, out);
}